// Round 1
// baseline (284.831 us; speedup 1.0000x reference)
//
#include <hip/hip_runtime.h>
#include <hip/hip_bf16.h>

// Problem dims
#define BB 16
#define NTOK 1024
#define EDIM 128
#define NHEAD 8
// M = BB*NTOK = 16384; qkv width 3072; inner 1024

typedef __bf16 bf16x8 __attribute__((ext_vector_type(8)));
typedef float f32x4 __attribute__((ext_vector_type(4)));

__device__ __forceinline__ unsigned short f2bf(float f) {
  union { __hip_bfloat16 h; unsigned short u; } cv;
  cv.h = __float2bfloat16(f);
  return cv.u;
}

__device__ __forceinline__ bf16x8 ld_frag(const unsigned short* p) {
  bf16x8 v;
  __builtin_memcpy(&v, __builtin_assume_aligned(p, 16), 16);
  return v;
}
__device__ __forceinline__ uint4 ld16(const unsigned short* p) {
  uint4 v;
  __builtin_memcpy(&v, __builtin_assume_aligned(p, 16), 16);
  return v;
}
__device__ __forceinline__ void st16(unsigned short* p, uint4 v) {
  __builtin_memcpy(__builtin_assume_aligned(p, 16), &v, 16);
}

// ---------------- LayerNorm + cast to bf16 -----------------
// one wave per row of 128; 4 rows per block
__global__ __launch_bounds__(256) void ln_kernel(const float* __restrict__ x,
                                                 const float* __restrict__ w,
                                                 const float* __restrict__ b,
                                                 unsigned short* __restrict__ xn) {
  int wave = threadIdx.x >> 6;
  int lane = threadIdx.x & 63;
  int row = blockIdx.x * 4 + wave;
  const float* xr = x + (size_t)row * 128;
  float2 v = *reinterpret_cast<const float2*>(xr + lane * 2);
  float s1 = v.x + v.y;
  float s2 = v.x * v.x + v.y * v.y;
#pragma unroll
  for (int off = 32; off > 0; off >>= 1) {
    s1 += __shfl_xor(s1, off, 64);
    s2 += __shfl_xor(s2, off, 64);
  }
  float mu = s1 * (1.0f / 128.0f);
  float var = s2 * (1.0f / 128.0f) - mu * mu;
  float rstd = rsqrtf(var + 1e-5f);
  float a0 = (v.x - mu) * rstd * w[lane * 2] + b[lane * 2];
  float a1 = (v.y - mu) * rstd * w[lane * 2 + 1] + b[lane * 2 + 1];
  unsigned int pk = (unsigned int)f2bf(a0) | ((unsigned int)f2bf(a1) << 16);
  *reinterpret_cast<unsigned int*>(xn + (size_t)row * 128 + lane * 2) = pk;
}

// ---------------- transpose + cast fp32[R][C] -> bf16[C][R] -----------------
__global__ __launch_bounds__(256) void tcast_kernel(const float* __restrict__ in,
                                                    unsigned short* __restrict__ out,
                                                    int R, int C) {
  __shared__ float tile[32][33];
  int tx = threadIdx.x & 31, ty = threadIdx.x >> 5;  // ty 0..7
  int c0 = blockIdx.x * 32, r0 = blockIdx.y * 32;
#pragma unroll
  for (int k = 0; k < 4; k++)
    tile[ty + 8 * k][tx] = in[(size_t)(r0 + ty + 8 * k) * C + c0 + tx];
  __syncthreads();
#pragma unroll
  for (int k = 0; k < 4; k++)
    out[(size_t)(c0 + ty + 8 * k) * R + r0 + tx] = f2bf(tile[tx][ty + 8 * k]);
}

// ---------------- QKV GEMM: qkv[16384][3072] = xn[16384][128] @ WqkvT^T ------
// Bt layout: wqkvT[3072][128] (row n holds column n of w_qkv). 64x128 tile.
__global__ __launch_bounds__(256) void qkv_gemm(const unsigned short* __restrict__ A,
                                                const unsigned short* __restrict__ Bt,
                                                unsigned short* __restrict__ C) {
  __shared__ unsigned short Al[64 * 136];
  __shared__ unsigned short Bl[128 * 136];
  int t = threadIdx.x;
  int i0 = blockIdx.x * 64, c0 = blockIdx.y * 128;
  int l = t & 15, rr = t >> 4;
#pragma unroll
  for (int p = 0; p < 4; p++) {
    int r = rr + 16 * p;
    st16(&Al[r * 136 + l * 8], ld16(&A[(size_t)(i0 + r) * 128 + l * 8]));
  }
#pragma unroll
  for (int p = 0; p < 8; p++) {
    int r = rr + 16 * p;
    st16(&Bl[r * 136 + l * 8], ld16(&Bt[(size_t)(c0 + r) * 128 + l * 8]));
  }
  __syncthreads();
  int w = t >> 6, lane = t & 63, l15 = lane & 15, quad = lane >> 4;
  int wy = (w >> 1) * 32, wx = (w & 1) * 64;
  const f32x4 fz = {0.f, 0.f, 0.f, 0.f};
  f32x4 acc[2][4];
#pragma unroll
  for (int i = 0; i < 2; i++)
#pragma unroll
    for (int j = 0; j < 4; j++) acc[i][j] = fz;
#pragma unroll
  for (int ks = 0; ks < 4; ks++) {
    bf16x8 af[2], bfr[4];
#pragma unroll
    for (int i = 0; i < 2; i++)
      af[i] = ld_frag(&Al[(wy + 16 * i + l15) * 136 + 32 * ks + quad * 8]);
#pragma unroll
    for (int j = 0; j < 4; j++)
      bfr[j] = ld_frag(&Bl[(wx + 16 * j + l15) * 136 + 32 * ks + quad * 8]);
#pragma unroll
    for (int i = 0; i < 2; i++)
#pragma unroll
      for (int j = 0; j < 4; j++)
        acc[i][j] = __builtin_amdgcn_mfma_f32_16x16x32_bf16(af[i], bfr[j], acc[i][j], 0, 0, 0);
  }
#pragma unroll
  for (int i = 0; i < 2; i++)
#pragma unroll
    for (int j = 0; j < 4; j++)
#pragma unroll
      for (int r = 0; r < 4; r++) {
        int row = i0 + wy + 16 * i + quad * 4 + r;
        int col = c0 + wx + 16 * j + l15;
        C[(size_t)row * 3072 + col] = f2bf(acc[i][j][r]);
      }
}

// ---------------- V transpose: Vt[b,h,d,n] = qkv[b,n, 2048 + h*128 + d] ------
__global__ __launch_bounds__(256) void vtrans_kernel(const unsigned short* __restrict__ qkv,
                                                     unsigned short* __restrict__ Vt) {
  __shared__ unsigned short tl[64][65];
  int t = threadIdx.x, tx = t & 63, ty = t >> 6;  // ty 0..3
  int n0 = blockIdx.x * 64, d0 = blockIdx.y * 64, bh = blockIdx.z;
  int b = bh >> 3, h = bh & 7;
  const unsigned short* in = qkv + (size_t)b * 1024 * 3072 + 2048 + h * 128;
#pragma unroll
  for (int k = 0; k < 16; k++)
    tl[ty + 4 * k][tx] = in[(size_t)(n0 + ty + 4 * k) * 3072 + d0 + tx];
  __syncthreads();
  unsigned short* ob = Vt + (size_t)bh * 128 * 1024;
#pragma unroll
  for (int k = 0; k < 16; k++)
    ob[(size_t)(d0 + ty + 4 * k) * 1024 + n0 + tx] = tl[tx][ty + 4 * k];
}

// ---------------- Flash attention -----------------
// block = (b, h, 64-row Q tile); 4 waves x 16 rows; KV tiles of 64.
__global__ __launch_bounds__(256) void attn_kernel(const unsigned short* __restrict__ qkv,
                                                   const unsigned short* __restrict__ Vt,
                                                   const float* __restrict__ scale,
                                                   unsigned short* __restrict__ aout) {
  __shared__ unsigned short Kl[64 * 136];
  __shared__ unsigned short Vl[128 * 72];
  __shared__ unsigned short Pl[64 * 72];
  int t = threadIdx.x;
  // XCD swizzle: all 16 q-tiles of one (b,h) land on the same XCD slot (mod 8)
  int slot = blockIdx.x;
  int xcd = slot & 7, idx = slot >> 3;
  int qt = idx & 15, bh = xcd + 8 * (idx >> 4);
  int b = bh >> 3, h = bh & 7;
  int q0 = qt * 64;
  float sc = scale[h];
  int w = t >> 6, lane = t & 63, l15 = lane & 15, quad = lane >> 4;

  // Q fragments in registers (A-operand layout)
  bf16x8 qf[4];
  {
    const unsigned short* qp = qkv + (size_t)(b * 1024 + q0 + 16 * w + l15) * 3072 + h * 128;
#pragma unroll
    for (int ks = 0; ks < 4; ks++) qf[ks] = ld_frag(qp + 32 * ks + quad * 8);
  }
  const f32x4 fz = {0.f, 0.f, 0.f, 0.f};
  f32x4 o[8];
#pragma unroll
  for (int i = 0; i < 8; i++) o[i] = fz;
  float mprev[4], lsum[4];
#pragma unroll
  for (int r = 0; r < 4; r++) { mprev[r] = -__builtin_inff(); lsum[r] = 0.f; }

  const unsigned short* kbase = qkv + (size_t)b * 1024 * 3072 + 1024 + h * 128;
  const unsigned short* vbase = Vt + (size_t)bh * 128 * 1024;
  int lk = t & 15, rrk = t >> 4;
  int lv = t & 7, rrv = t >> 3;

  for (int kt = 0; kt < 16; kt++) {
    int k0 = kt * 64;
    uint4 kreg[4], vreg[4];
#pragma unroll
    for (int p = 0; p < 4; p++)
      kreg[p] = ld16(kbase + (size_t)(k0 + rrk + 16 * p) * 3072 + lk * 8);
#pragma unroll
    for (int p = 0; p < 4; p++)
      vreg[p] = ld16(vbase + (size_t)(rrv + 32 * p) * 1024 + k0 + lv * 8);
    __syncthreads();  // previous tile's LDS reads done
#pragma unroll
    for (int p = 0; p < 4; p++) st16(&Kl[(rrk + 16 * p) * 136 + lk * 8], kreg[p]);
#pragma unroll
    for (int p = 0; p < 4; p++) st16(&Vl[(rrv + 32 * p) * 72 + lv * 8], vreg[p]);
    __syncthreads();  // staging visible

    // S = Q K^T (C-layout: col=l15, row=quad*4+r)
    float sv[4][4];
#pragma unroll
    for (int ct = 0; ct < 4; ct++) {
      f32x4 acc = fz;
#pragma unroll
      for (int ks = 0; ks < 4; ks++) {
        bf16x8 kf = ld_frag(&Kl[(16 * ct + l15) * 136 + 32 * ks + quad * 8]);
        acc = __builtin_amdgcn_mfma_f32_16x16x32_bf16(qf[ks], kf, acc, 0, 0, 0);
      }
#pragma unroll
      for (int r = 0; r < 4; r++) sv[ct][r] = acc[r] * sc;
    }
    // diagonal mask (reference sets diag logits to -FLT_MAX -> weight 0)
    int grow = q0 + 16 * w + quad * 4;
    int gcolb = k0 + l15;
#pragma unroll
    for (int ct = 0; ct < 4; ct++)
#pragma unroll
      for (int r = 0; r < 4; r++)
        if (grow + r == gcolb + 16 * ct) sv[ct][r] = -__builtin_inff();

    // online softmax (row stats via 16-lane butterfly within each quad-group)
    float alpha[4];
#pragma unroll
    for (int r = 0; r < 4; r++) {
      float m = sv[0][r];
#pragma unroll
      for (int ct = 1; ct < 4; ct++) m = fmaxf(m, sv[ct][r]);
#pragma unroll
      for (int off = 1; off < 16; off <<= 1) m = fmaxf(m, __shfl_xor(m, off, 64));
      float mn = fmaxf(mprev[r], m);
      alpha[r] = __expf(mprev[r] - mn);
      mprev[r] = mn;
      float rs = 0.f;
#pragma unroll
      for (int ct = 0; ct < 4; ct++) {
        float p = __expf(sv[ct][r] - mn);
        sv[ct][r] = p;
        rs += p;
      }
#pragma unroll
      for (int off = 1; off < 16; off <<= 1) rs += __shfl_xor(rs, off, 64);
      lsum[r] = lsum[r] * alpha[r] + rs;
    }
#pragma unroll
    for (int i = 0; i < 8; i++)
#pragma unroll
      for (int r = 0; r < 4; r++) o[i][r] *= alpha[r];

    // P: C-layout -> LDS -> A-layout (each wave touches only its own 16 rows)
#pragma unroll
    for (int ct = 0; ct < 4; ct++)
#pragma unroll
      for (int r = 0; r < 4; r++)
        Pl[(16 * w + quad * 4 + r) * 72 + 16 * ct + l15] = f2bf(sv[ct][r]);
    __syncthreads();

    // O += P V
    bf16x8 pa[2];
#pragma unroll
    for (int ks = 0; ks < 2; ks++)
      pa[ks] = ld_frag(&Pl[(16 * w + l15) * 72 + 32 * ks + quad * 8]);
#pragma unroll
    for (int c8 = 0; c8 < 8; c8++) {
#pragma unroll
      for (int ks = 0; ks < 2; ks++) {
        bf16x8 vf = ld_frag(&Vl[(16 * c8 + l15) * 72 + 32 * ks + quad * 8]);
        o[c8] = __builtin_amdgcn_mfma_f32_16x16x32_bf16(pa[ks], vf, o[c8], 0, 0, 0);
      }
    }
  }

  // epilogue: aout[b, n, h*128 + d] bf16
#pragma unroll
  for (int r = 0; r < 4; r++) {
    float rl = 1.0f / lsum[r];
    int row = b * 1024 + q0 + 16 * w + quad * 4 + r;
#pragma unroll
    for (int c8 = 0; c8 < 8; c8++) {
      int col = h * 128 + 16 * c8 + l15;
      aout[(size_t)row * 1024 + col] = f2bf(o[c8][r] * rl);
    }
  }
}

// ---------------- output projection: out = aout @ w_proj + b_proj (fp32) ----
__global__ __launch_bounds__(256) void proj_gemm(const unsigned short* __restrict__ A,
                                                 const unsigned short* __restrict__ Bt,
                                                 const float* __restrict__ bias,
                                                 float* __restrict__ out) {
  __shared__ unsigned short Al[64 * 136];
  __shared__ unsigned short Bl[128 * 136];
  int t = threadIdx.x;
  int i0 = blockIdx.x * 64;
  int w = t >> 6, lane = t & 63, l15 = lane & 15, quad = lane >> 4;
  int wy = (w >> 1) * 32, wx = (w & 1) * 64;
  const f32x4 fz = {0.f, 0.f, 0.f, 0.f};
  f32x4 acc[2][4];
#pragma unroll
  for (int i = 0; i < 2; i++)
#pragma unroll
    for (int j = 0; j < 4; j++) acc[i][j] = fz;
  int l = t & 15, rr = t >> 4;
  for (int kb = 0; kb < 8; kb++) {
    int k0 = kb * 128;
    uint4 areg[4], breg[8];
#pragma unroll
    for (int p = 0; p < 4; p++)
      areg[p] = ld16(&A[(size_t)(i0 + rr + 16 * p) * 1024 + k0 + l * 8]);
#pragma unroll
    for (int p = 0; p < 8; p++)
      breg[p] = ld16(&Bt[(size_t)(rr + 16 * p) * 1024 + k0 + l * 8]);
    __syncthreads();
#pragma unroll
    for (int p = 0; p < 4; p++) st16(&Al[(rr + 16 * p) * 136 + l * 8], areg[p]);
#pragma unroll
    for (int p = 0; p < 8; p++) st16(&Bl[(rr + 16 * p) * 136 + l * 8], breg[p]);
    __syncthreads();
#pragma unroll
    for (int ks = 0; ks < 4; ks++) {
      bf16x8 af[2], bfr[4];
#pragma unroll
      for (int i = 0; i < 2; i++)
        af[i] = ld_frag(&Al[(wy + 16 * i + l15) * 136 + 32 * ks + quad * 8]);
#pragma unroll
      for (int j = 0; j < 4; j++)
        bfr[j] = ld_frag(&Bl[(wx + 16 * j + l15) * 136 + 32 * ks + quad * 8]);
#pragma unroll
      for (int i = 0; i < 2; i++)
#pragma unroll
        for (int j = 0; j < 4; j++)
          acc[i][j] = __builtin_amdgcn_mfma_f32_16x16x32_bf16(af[i], bfr[j], acc[i][j], 0, 0, 0);
    }
  }
#pragma unroll
  for (int i = 0; i < 2; i++)
#pragma unroll
    for (int j = 0; j < 4; j++) {
      int col = wx + 16 * j + l15;
      float bv = bias[col];
#pragma unroll
      for (int r = 0; r < 4; r++) {
        int row = i0 + wy + 16 * i + quad * 4 + r;
        out[(size_t)row * 128 + col] = acc[i][j][r] + bv;
      }
    }
}

extern "C" void kernel_launch(void* const* d_in, const int* in_sizes, int n_in,
                              void* d_out, int out_size, void* d_ws, size_t ws_size,
                              hipStream_t stream) {
  const float* x      = (const float*)d_in[0];
  const float* ln_w   = (const float*)d_in[1];
  const float* ln_b   = (const float*)d_in[2];
  const float* w_qkv  = (const float*)d_in[3];
  const float* scale  = (const float*)d_in[4];
  const float* w_proj = (const float*)d_in[5];
  const float* b_proj = (const float*)d_in[6];
  float* out = (float*)d_out;

  char* ws = (char*)d_ws;
  unsigned short* xn     = (unsigned short*)(ws);               // 16384*128   bf16 = 4 MB
  unsigned short* wqkvT  = (unsigned short*)(ws + 4194304);     // 3072*128    bf16
  unsigned short* wprojT = (unsigned short*)(ws + 4980736);     // 128*1024    bf16
  unsigned short* qkv    = (unsigned short*)(ws + 5242880);     // 16384*3072  bf16 = 96 MB
  unsigned short* Vt     = (unsigned short*)(ws + 105906176);   // 128*128*1024 bf16 = 32 MB
  unsigned short* aout   = (unsigned short*)(ws + 139460608);   // 16384*1024  bf16 = 32 MB
  // total ws use: ~173 MB

  ln_kernel<<<dim3(4096), dim3(256), 0, stream>>>(x, ln_w, ln_b, xn);
  tcast_kernel<<<dim3(96, 4), dim3(256), 0, stream>>>(w_qkv, wqkvT, 128, 3072);
  tcast_kernel<<<dim3(4, 32), dim3(256), 0, stream>>>(w_proj, wprojT, 1024, 128);
  qkv_gemm<<<dim3(256, 24), dim3(256), 0, stream>>>(xn, wqkvT, qkv);
  vtrans_kernel<<<dim3(16, 2, 128), dim3(256), 0, stream>>>(qkv, Vt);
  attn_kernel<<<dim3(2048), dim3(256), 0, stream>>>(qkv, Vt, scale, aout);
  proj_gemm<<<dim3(256), dim3(256), 0, stream>>>(aout, wprojT, b_proj, out);
}

// Round 2
// 216.133 us; speedup vs baseline: 1.3178x; 1.3178x over previous
//
#include <hip/hip_runtime.h>
#include <hip/hip_bf16.h>

// Problem dims: B=16, N=1024, E=d_head=128, H=8; M = 16384 rows
typedef __bf16 bf16x8 __attribute__((ext_vector_type(8)));
typedef float f32x4 __attribute__((ext_vector_type(4)));

__device__ __forceinline__ unsigned short f2bf(float f) {
  union { __hip_bfloat16 h; unsigned short u; } cv;
  cv.h = __float2bfloat16(f);
  return cv.u;
}

__device__ __forceinline__ bf16x8 ld_frag(const unsigned short* p) {
  bf16x8 v;
  __builtin_memcpy(&v, __builtin_assume_aligned(p, 16), 16);
  return v;
}
__device__ __forceinline__ uint4 ld16(const unsigned short* p) {
  uint4 v;
  __builtin_memcpy(&v, __builtin_assume_aligned(p, 16), 16);
  return v;
}
__device__ __forceinline__ void st16(unsigned short* p, uint4 v) {
  __builtin_memcpy(__builtin_assume_aligned(p, 16), &v, 16);
}

// ---------------- LayerNorm + cast to bf16 -----------------
__global__ __launch_bounds__(256) void ln_kernel(const float* __restrict__ x,
                                                 const float* __restrict__ w,
                                                 const float* __restrict__ b,
                                                 unsigned short* __restrict__ xn) {
  int wave = threadIdx.x >> 6;
  int lane = threadIdx.x & 63;
  int row = blockIdx.x * 4 + wave;
  const float* xr = x + (size_t)row * 128;
  float2 v = *reinterpret_cast<const float2*>(xr + lane * 2);
  float s1 = v.x + v.y;
  float s2 = v.x * v.x + v.y * v.y;
#pragma unroll
  for (int off = 32; off > 0; off >>= 1) {
    s1 += __shfl_xor(s1, off, 64);
    s2 += __shfl_xor(s2, off, 64);
  }
  float mu = s1 * (1.0f / 128.0f);
  float var = s2 * (1.0f / 128.0f) - mu * mu;
  float rstd = rsqrtf(var + 1e-5f);
  float a0 = (v.x - mu) * rstd * w[lane * 2] + b[lane * 2];
  float a1 = (v.y - mu) * rstd * w[lane * 2 + 1] + b[lane * 2 + 1];
  unsigned int pk = (unsigned int)f2bf(a0) | ((unsigned int)f2bf(a1) << 16);
  *reinterpret_cast<unsigned int*>(xn + (size_t)row * 128 + lane * 2) = pk;
}

// ---------------- transpose + cast fp32[R][C] -> bf16[C][R] -----------------
__global__ __launch_bounds__(256) void tcast_kernel(const float* __restrict__ in,
                                                    unsigned short* __restrict__ out,
                                                    int R, int C) {
  __shared__ float tile[32][33];
  int tx = threadIdx.x & 31, ty = threadIdx.x >> 5;
  int c0 = blockIdx.x * 32, r0 = blockIdx.y * 32;
#pragma unroll
  for (int k = 0; k < 4; k++)
    tile[ty + 8 * k][tx] = in[(size_t)(r0 + ty + 8 * k) * C + c0 + tx];
  __syncthreads();
#pragma unroll
  for (int k = 0; k < 4; k++)
    out[(size_t)(c0 + ty + 8 * k) * R + r0 + tx] = f2bf(tile[tx][ty + 8 * k]);
}

// ---------------- QKV GEMM ----------------
// Q,K cols (0..2047) -> qk[16384][2048]; V cols -> Vt[bh=128][d=128][n=1024]
__global__ __launch_bounds__(256) void qkv_gemm(const unsigned short* __restrict__ A,
                                                const unsigned short* __restrict__ Bt,
                                                unsigned short* __restrict__ qk,
                                                unsigned short* __restrict__ Vt) {
  __shared__ unsigned short Al[64 * 136];
  __shared__ unsigned short Bl[128 * 136];
  int t = threadIdx.x;
  int i0 = blockIdx.x * 64, c0 = blockIdx.y * 128;
  int l = t & 15, rr = t >> 4;
#pragma unroll
  for (int p = 0; p < 4; p++) {
    int r = rr + 16 * p;
    st16(&Al[r * 136 + l * 8], ld16(&A[(size_t)(i0 + r) * 128 + l * 8]));
  }
#pragma unroll
  for (int p = 0; p < 8; p++) {
    int r = rr + 16 * p;
    st16(&Bl[r * 136 + l * 8], ld16(&Bt[(size_t)(c0 + r) * 128 + l * 8]));
  }
  __syncthreads();
  int w = t >> 6, lane = t & 63, l15 = lane & 15, quad = lane >> 4;
  int wy = (w >> 1) * 32, wx = (w & 1) * 64;
  const f32x4 fz = {0.f, 0.f, 0.f, 0.f};
  f32x4 acc[2][4];
#pragma unroll
  for (int i = 0; i < 2; i++)
#pragma unroll
    for (int j = 0; j < 4; j++) acc[i][j] = fz;
#pragma unroll
  for (int ks = 0; ks < 4; ks++) {
    bf16x8 af[2], bfr[4];
#pragma unroll
    for (int i = 0; i < 2; i++)
      af[i] = ld_frag(&Al[(wy + 16 * i + l15) * 136 + 32 * ks + quad * 8]);
#pragma unroll
    for (int j = 0; j < 4; j++)
      bfr[j] = ld_frag(&Bl[(wx + 16 * j + l15) * 136 + 32 * ks + quad * 8]);
#pragma unroll
    for (int i = 0; i < 2; i++)
#pragma unroll
      for (int j = 0; j < 4; j++)
        acc[i][j] = __builtin_amdgcn_mfma_f32_16x16x32_bf16(af[i], bfr[j], acc[i][j], 0, 0, 0);
  }
  if (blockIdx.y < 16) {
    // Q/K block: write qk rows stride 2048
#pragma unroll
    for (int i = 0; i < 2; i++)
#pragma unroll
      for (int j = 0; j < 4; j++)
#pragma unroll
        for (int r = 0; r < 4; r++) {
          int row = i0 + wy + 16 * i + quad * 4 + r;
          int col = c0 + wx + 16 * j + l15;
          qk[(size_t)row * 2048 + col] = f2bf(acc[i][j][r]);
        }
  } else {
    // V block: scatter into Vt[bh][d][n], 4 consecutive n packed per store
    int vc0 = (blockIdx.y - 16) * 128;
#pragma unroll
    for (int i = 0; i < 2; i++)
#pragma unroll
      for (int j = 0; j < 4; j++) {
        int vcol = vc0 + wx + 16 * j + l15;   // 0..1023
        int hh = vcol >> 7, dd = vcol & 127;
        int row0 = i0 + wy + 16 * i + quad * 4;
        int bb = row0 >> 10, nn = row0 & 1023;
        ushort4 pk;
        pk.x = f2bf(acc[i][j][0]); pk.y = f2bf(acc[i][j][1]);
        pk.z = f2bf(acc[i][j][2]); pk.w = f2bf(acc[i][j][3]);
        *reinterpret_cast<ushort4*>(Vt + (size_t)(bb * 8 + hh) * 131072 +
                                    (size_t)dd * 1024 + nn) = pk;
      }
  }
}

// ---------------- Flash attention (no-max softmax, 32 Q-rows/wave) ----------
// block = (b,h, 128-row Q tile); 4 waves x 32 rows; KV tiles of 64.
__global__ __launch_bounds__(256, 3) void attn_kernel(const unsigned short* __restrict__ qk,
                                                      const unsigned short* __restrict__ Vt,
                                                      const float* __restrict__ scale,
                                                      unsigned short* __restrict__ aout) {
  __shared__ unsigned short Kl[64 * 136];
  __shared__ unsigned short Vl[128 * 72];
  __shared__ unsigned short Pl[128 * 72];
  int t = threadIdx.x;
  int idx = blockIdx.x;
  // q-tiles of one bh at blockIdx stride 128 (=0 mod 8) -> same XCD slot
  int bh = idx & 127, qt = idx >> 7;
  int b = bh >> 3, h = bh & 7;
  int q0 = qt * 128;
  float sc = scale[h];
  int w = t >> 6, lane = t & 63, l15 = lane & 15, quad = lane >> 4;

  // Q fragments in registers (A-layout), 2 row-groups of 16 per wave
  bf16x8 qf[2][4];
#pragma unroll
  for (int g = 0; g < 2; g++) {
    const unsigned short* qp =
        qk + (size_t)(b * 1024 + q0 + 32 * w + 16 * g + l15) * 2048 + h * 128;
#pragma unroll
    for (int ks = 0; ks < 4; ks++) qf[g][ks] = ld_frag(qp + 32 * ks + quad * 8);
  }
  const f32x4 fz = {0.f, 0.f, 0.f, 0.f};
  f32x4 o[2][8];
#pragma unroll
  for (int g = 0; g < 2; g++)
#pragma unroll
    for (int i = 0; i < 8; i++) o[g][i] = fz;
  float plsum[2][4];
#pragma unroll
  for (int g = 0; g < 2; g++)
#pragma unroll
    for (int r = 0; r < 4; r++) plsum[g][r] = 0.f;

  const unsigned short* kbase = qk + (size_t)b * 1024 * 2048 + 1024 + h * 128;
  const unsigned short* vbase = Vt + (size_t)bh * 131072;
  int lk = t & 15, rrk = t >> 4;
  int lv = t & 7, rrv = t >> 3;

  for (int kt = 0; kt < 16; kt++) {
    int k0 = kt * 64;
    uint4 kreg[4], vreg[4];
#pragma unroll
    for (int p = 0; p < 4; p++)
      kreg[p] = ld16(kbase + (size_t)(k0 + rrk + 16 * p) * 2048 + lk * 8);
#pragma unroll
    for (int p = 0; p < 4; p++)
      vreg[p] = ld16(vbase + (size_t)(rrv + 32 * p) * 1024 + k0 + lv * 8);
    __syncthreads();  // previous tile's LDS reads done
#pragma unroll
    for (int p = 0; p < 4; p++) st16(&Kl[(rrk + 16 * p) * 136 + lk * 8], kreg[p]);
#pragma unroll
    for (int p = 0; p < 4; p++) st16(&Vl[(rrv + 32 * p) * 72 + lv * 8], vreg[p]);
    __syncthreads();  // staging visible

    // S = Q K^T per 16-col tile; kf shared across both row groups
#pragma unroll
    for (int ct = 0; ct < 4; ct++) {
      f32x4 acc0 = fz, acc1 = fz;
#pragma unroll
      for (int ks = 0; ks < 4; ks++) {
        bf16x8 kf = ld_frag(&Kl[(16 * ct + l15) * 136 + 32 * ks + quad * 8]);
        acc0 = __builtin_amdgcn_mfma_f32_16x16x32_bf16(qf[0][ks], kf, acc0, 0, 0, 0);
        acc1 = __builtin_amdgcn_mfma_f32_16x16x32_bf16(qf[1][ks], kf, acc1, 0, 0, 0);
      }
      // no-max softmax: p = exp(s*sc); diagonal -> 0; per-lane partial row sums
#pragma unroll
      for (int g = 0; g < 2; g++) {
        f32x4 a = g ? acc1 : acc0;
        bool dj = (q0 + 32 * w + 16 * g) == (k0 + 16 * ct);  // band hits diagonal?
#pragma unroll
        for (int r = 0; r < 4; r++) {
          float p = __expf(a[r] * sc);
          if (dj && (quad * 4 + r) == l15) p = 0.f;
          plsum[g][r] += p;
          Pl[(32 * w + 16 * g + quad * 4 + r) * 72 + 16 * ct + l15] = f2bf(p);
        }
      }
    }
    __syncthreads();  // P visible

    // O += P V ; vf shared across both row groups
    bf16x8 pa[2][2];
#pragma unroll
    for (int g = 0; g < 2; g++)
#pragma unroll
      for (int ks2 = 0; ks2 < 2; ks2++)
        pa[g][ks2] = ld_frag(&Pl[(32 * w + 16 * g + l15) * 72 + 32 * ks2 + quad * 8]);
#pragma unroll
    for (int c8 = 0; c8 < 8; c8++) {
#pragma unroll
      for (int ks2 = 0; ks2 < 2; ks2++) {
        bf16x8 vf = ld_frag(&Vl[(16 * c8 + l15) * 72 + 32 * ks2 + quad * 8]);
        o[0][c8] = __builtin_amdgcn_mfma_f32_16x16x32_bf16(pa[0][ks2], vf, o[0][c8], 0, 0, 0);
        o[1][c8] = __builtin_amdgcn_mfma_f32_16x16x32_bf16(pa[1][ks2], vf, o[1][c8], 0, 0, 0);
      }
    }
  }

  // epilogue: row-sum butterfly (only here), normalize, write bf16
#pragma unroll
  for (int g = 0; g < 2; g++)
#pragma unroll
    for (int r = 0; r < 4; r++) {
      float s = plsum[g][r];
#pragma unroll
      for (int off = 1; off < 16; off <<= 1) s += __shfl_xor(s, off, 64);
      float rl = 1.0f / s;
      int row = b * 1024 + q0 + 32 * w + 16 * g + quad * 4 + r;
#pragma unroll
      for (int c8 = 0; c8 < 8; c8++) {
        int col = h * 128 + 16 * c8 + l15;
        aout[(size_t)row * 1024 + col] = f2bf(o[g][c8][r] * rl);
      }
    }
}

// ---------------- output projection: out = aout @ w_proj + b_proj (fp32) ----
__global__ __launch_bounds__(256) void proj_gemm(const unsigned short* __restrict__ A,
                                                 const unsigned short* __restrict__ Bt,
                                                 const float* __restrict__ bias,
                                                 float* __restrict__ out) {
  __shared__ unsigned short Al[64 * 136];
  __shared__ unsigned short Bl[128 * 136];
  int t = threadIdx.x;
  int i0 = blockIdx.x * 64;
  int w = t >> 6, lane = t & 63, l15 = lane & 15, quad = lane >> 4;
  int wy = (w >> 1) * 32, wx = (w & 1) * 64;
  const f32x4 fz = {0.f, 0.f, 0.f, 0.f};
  f32x4 acc[2][4];
#pragma unroll
  for (int i = 0; i < 2; i++)
#pragma unroll
    for (int j = 0; j < 4; j++) acc[i][j] = fz;
  int l = t & 15, rr = t >> 4;
  for (int kb = 0; kb < 8; kb++) {
    int k0 = kb * 128;
    uint4 areg[4], breg[8];
#pragma unroll
    for (int p = 0; p < 4; p++)
      areg[p] = ld16(&A[(size_t)(i0 + rr + 16 * p) * 1024 + k0 + l * 8]);
#pragma unroll
    for (int p = 0; p < 8; p++)
      breg[p] = ld16(&Bt[(size_t)(rr + 16 * p) * 1024 + k0 + l * 8]);
    __syncthreads();
#pragma unroll
    for (int p = 0; p < 4; p++) st16(&Al[(rr + 16 * p) * 136 + l * 8], areg[p]);
#pragma unroll
    for (int p = 0; p < 8; p++) st16(&Bl[(rr + 16 * p) * 136 + l * 8], breg[p]);
    __syncthreads();
#pragma unroll
    for (int ks = 0; ks < 4; ks++) {
      bf16x8 af[2], bfr[4];
#pragma unroll
      for (int i = 0; i < 2; i++)
        af[i] = ld_frag(&Al[(wy + 16 * i + l15) * 136 + 32 * ks + quad * 8]);
#pragma unroll
      for (int j = 0; j < 4; j++)
        bfr[j] = ld_frag(&Bl[(wx + 16 * j + l15) * 136 + 32 * ks + quad * 8]);
#pragma unroll
      for (int i = 0; i < 2; i++)
#pragma unroll
        for (int j = 0; j < 4; j++)
          acc[i][j] = __builtin_amdgcn_mfma_f32_16x16x32_bf16(af[i], bfr[j], acc[i][j], 0, 0, 0);
    }
  }
#pragma unroll
  for (int i = 0; i < 2; i++)
#pragma unroll
    for (int j = 0; j < 4; j++) {
      int col = wx + 16 * j + l15;
      float bv = bias[col];
#pragma unroll
      for (int r = 0; r < 4; r++) {
        int row = i0 + wy + 16 * i + quad * 4 + r;
        out[(size_t)row * 128 + col] = acc[i][j][r] + bv;
      }
    }
}

extern "C" void kernel_launch(void* const* d_in, const int* in_sizes, int n_in,
                              void* d_out, int out_size, void* d_ws, size_t ws_size,
                              hipStream_t stream) {
  const float* x      = (const float*)d_in[0];
  const float* ln_w   = (const float*)d_in[1];
  const float* ln_b   = (const float*)d_in[2];
  const float* w_qkv  = (const float*)d_in[3];
  const float* scale  = (const float*)d_in[4];
  const float* w_proj = (const float*)d_in[5];
  const float* b_proj = (const float*)d_in[6];
  float* out = (float*)d_out;

  char* ws = (char*)d_ws;
  unsigned short* xn     = (unsigned short*)(ws);               // 4 MB
  unsigned short* wqkvT  = (unsigned short*)(ws + 4194304);     // 768 KB
  unsigned short* wprojT = (unsigned short*)(ws + 4980736);     // 256 KB
  unsigned short* qk     = (unsigned short*)(ws + 5242880);     // 64 MB [16384][2048]
  unsigned short* Vt     = (unsigned short*)(ws + 72351744);    // 32 MB [128][128][1024]
  unsigned short* aout   = (unsigned short*)(ws + 105906176);   // 32 MB
  // total ws use: ~139 MB

  ln_kernel<<<dim3(4096), dim3(256), 0, stream>>>(x, ln_w, ln_b, xn);
  tcast_kernel<<<dim3(96, 4), dim3(256), 0, stream>>>(w_qkv, wqkvT, 128, 3072);
  tcast_kernel<<<dim3(4, 32), dim3(256), 0, stream>>>(w_proj, wprojT, 1024, 128);
  qkv_gemm<<<dim3(256, 24), dim3(256), 0, stream>>>(xn, wqkvT, qk, Vt);
  attn_kernel<<<dim3(1024), dim3(256), 0, stream>>>(qk, Vt, scale, aout);
  proj_gemm<<<dim3(256), dim3(256), 0, stream>>>(aout, wprojT, b_proj, out);
}